// Round 10
// baseline (273.639 us; speedup 1.0000x reference)
//
#include <hip/hip_runtime.h>
#include <hip/hip_bf16.h>
#include <math.h>

// B=4, N=4096, F=512, C=64. M = B*N = 16384 rows.
#define M_ROWS 16384
#define F_DIM 512
#define C_DIM 64

typedef short bf16x8 __attribute__((ext_vector_type(8)));
typedef float floatx4 __attribute__((ext_vector_type(4)));
typedef unsigned short ushortx8 __attribute__((ext_vector_type(8)));
typedef unsigned short ushortx4 __attribute__((ext_vector_type(4)));

static __device__ __forceinline__ unsigned short f2bf(float x) {
    __hip_bfloat16 h = __float2bfloat16(x);   // RN
    return *reinterpret_cast<unsigned short*>(&h);
}
static __device__ __forceinline__ float bf2f(unsigned short h) {
    unsigned int u = ((unsigned int)h) << 16;
    return __builtin_bit_cast(float, u);
}

// LDS-only barrier: global loads stay in flight (no vmcnt(0) drain).
static __device__ __forceinline__ void lgkm_barrier() {
    asm volatile("s_waitcnt lgkmcnt(0)\n\ts_barrier" ::: "memory");
}

// ---------------------------------------------------------------------------
// Frag-linear layouts (MFMA B-operand order): element (n,k) of a 16-col group
// lives at lane=(k>>3&3)*16+(n&15), j=k&7 -> [group][lane][8] contiguous.
//   wt    : group = (c>>4)*16 + (k>>5)            (640 cols x 512 k)
//   h_sw  : [b][mtile(64)][group=(Fcol>>4)*2+(mloc>>5)][lane][8]
// ---------------------------------------------------------------------------

// Kernel 0: weight transpose + bf16 hi/lo split -> frag-linear.
__global__ __launch_bounds__(64) void prep_w_kernel(
    const float* __restrict__ Wf, const float* __restrict__ Wg,
    const float* __restrict__ Wh,
    unsigned short* __restrict__ wt_hi, unsigned short* __restrict__ wt_lo)
{
    const int c = blockIdx.x;
    const int t = threadIdx.x;
    const float* W; int ld, cl;
    if (c < 64)       { W = Wf; ld = C_DIM; cl = c; }
    else if (c < 128) { W = Wg; ld = C_DIM; cl = c - 64; }
    else              { W = Wh; ld = F_DIM; cl = c - 128; }
    const int ng = c >> 4, l16 = c & 15;
    for (int k = t; k < F_DIM; k += 64) {
        const float x = W[(size_t)k * ld + cl];
        const unsigned short h = f2bf(x);
        const int kh = k >> 5, qd = (k >> 3) & 3, j = k & 7;
        const size_t off = (((size_t)(ng * 16 + kh) * 64) + qd * 16 + l16) * 8 + j;
        wt_hi[off] = h;
        wt_lo[off] = f2bf(x - bf2f(h));
    }
}

// ---------------------------------------------------------------------------
// Kernel 1: MFMA embed GEMM — R8's verified version (best measured rest).
// 64 rows x 128 cols per block. blockIdx.y: 0 -> f|g fused (hi/lo 3-MFMA
// path), 1..4 -> h cols (y-1)*128. Wave w owns cols w*32..+32.
// ---------------------------------------------------------------------------
#define BM 64
#define LDK 72

__global__ __launch_bounds__(256, 4) void embed_mfma_kernel(
    const float* __restrict__ V,
    const unsigned short* __restrict__ wt_hi, const unsigned short* __restrict__ wt_lo,
    const float* __restrict__ bf, const float* __restrict__ bg,
    const float* __restrict__ bh,
    unsigned short* __restrict__ f_bf, unsigned short* __restrict__ g_bf,
    unsigned short* __restrict__ h_sw)
{
    __shared__ __align__(16) unsigned short a_hi[BM][LDK];
    __shared__ __align__(16) unsigned short a_lo[BM][LDK];

    const int t  = threadIdx.x;
    const int R0 = blockIdx.x * BM;
    const bool fg = (blockIdx.y == 0);
    const int cbase = fg ? 0 : blockIdx.y * 128;   // wt col base (g at 64, h at 128+)

    const int w = t >> 6, lane = t & 63, quad = lane >> 4, l16 = lane & 15;

    floatx4 acc[4][2];
    #pragma unroll
    for (int rt = 0; rt < 4; ++rt)
        #pragma unroll
        for (int c = 0; c < 2; ++c)
            acc[rt][c] = (floatx4){0.f, 0.f, 0.f, 0.f};

    const int arow = t >> 4;          // 0..15 (+16/round)
    const int acol = (t & 15) * 4;    // float index (16 B chunks)
    const int ng0  = (cbase >> 4) + w * 2;

    #pragma unroll 1
    for (int k0 = 0; k0 < F_DIM; k0 += 64) {
        lgkm_barrier();   // protect previous iteration's a-frag reads
        // ---- stage A: V fp32 -> bf16 hi/lo in LDS ----
        #pragma unroll
        for (int rr = 0; rr < 4; ++rr) {
            const int row = rr * 16 + arow;
            const float4 x = *(const float4*)(V + (size_t)(R0 + row) * F_DIM + k0 + acol);
            const float xs[4] = {x.x, x.y, x.z, x.w};
            ushortx4 hi, lo;
            #pragma unroll
            for (int jj = 0; jj < 4; ++jj) {
                const unsigned short hb2 = f2bf(xs[jj]);
                hi[jj] = hb2;
                lo[jj] = f2bf(xs[jj] - bf2f(hb2));
            }
            *(ushortx4*)&a_hi[row][acol] = hi;
            if (fg) *(ushortx4*)&a_lo[row][acol] = lo;
        }
        lgkm_barrier();
        // ---- compute ----
        #pragma unroll
        for (int kk = 0; kk < 2; ++kk) {
            const int kh = (k0 >> 5) + kk;
            const bf16x8 b0 = *(const bf16x8*)(wt_hi + (((size_t)(ng0 * 16 + kh)) * 64 + lane) * 8);
            const bf16x8 b1 = *(const bf16x8*)(wt_hi + (((size_t)((ng0 + 1) * 16 + kh)) * 64 + lane) * 8);
            bf16x8 ah[4];
            #pragma unroll
            for (int rt = 0; rt < 4; ++rt)
                ah[rt] = *(const bf16x8*)&a_hi[rt * 16 + l16][kk * 32 + quad * 8];
            #pragma unroll
            for (int rt = 0; rt < 4; ++rt) {
                acc[rt][0] = __builtin_amdgcn_mfma_f32_16x16x32_bf16(ah[rt], b0, acc[rt][0], 0, 0, 0);
                acc[rt][1] = __builtin_amdgcn_mfma_f32_16x16x32_bf16(ah[rt], b1, acc[rt][1], 0, 0, 0);
            }
            if (fg) {
                const bf16x8 c0 = *(const bf16x8*)(wt_lo + (((size_t)(ng0 * 16 + kh)) * 64 + lane) * 8);
                const bf16x8 c1 = *(const bf16x8*)(wt_lo + (((size_t)((ng0 + 1) * 16 + kh)) * 64 + lane) * 8);
                bf16x8 al[4];
                #pragma unroll
                for (int rt = 0; rt < 4; ++rt)
                    al[rt] = *(const bf16x8*)&a_lo[rt * 16 + l16][kk * 32 + quad * 8];
                #pragma unroll
                for (int rt = 0; rt < 4; ++rt) {
                    acc[rt][0] = __builtin_amdgcn_mfma_f32_16x16x32_bf16(ah[rt], c0, acc[rt][0], 0, 0, 0);
                    acc[rt][0] = __builtin_amdgcn_mfma_f32_16x16x32_bf16(al[rt], b0, acc[rt][0], 0, 0, 0);
                    acc[rt][1] = __builtin_amdgcn_mfma_f32_16x16x32_bf16(ah[rt], c1, acc[rt][1], 0, 0, 0);
                    acc[rt][1] = __builtin_amdgcn_mfma_f32_16x16x32_bf16(al[rt], b1, acc[rt][1], 0, 0, 0);
                }
            }
        }
    }

    // ---- epilogue: bias + relu + bf16, route by wt column ----
    #pragma unroll
    for (int rt = 0; rt < 4; ++rt) {
        #pragma unroll
        for (int c = 0; c < 2; ++c) {
            const int wtc  = cbase + w * 32 + c * 16 + l16;   // 0..639
            const int rowl = rt * 16 + quad * 4;
            const float bias = fg ? (wtc < 64 ? bf[wtc] : bg[wtc - 64]) : bh[wtc - 128];
            const floatx4 v = acc[rt][c];
            if (fg) {
                unsigned short* dst = (wtc < 64) ? (f_bf + wtc) : (g_bf + wtc - 64);
                #pragma unroll
                for (int r = 0; r < 4; ++r) {
                    const float z = v[r] + bias;
                    dst[(size_t)(R0 + rowl + r) * C_DIM] = f2bf(z > 0.f ? z : 0.f);
                }
            } else {
                const int hc   = wtc - 128;                   // global F col
                const int grow = R0 + rowl;
                const int b    = grow >> 12, rl = grow & 4095;
                const int T    = rl >> 6, mloc = rl & 63;
                const int kh2  = mloc >> 5, q2 = (mloc >> 3) & 3, j0 = mloc & 7;
                ushortx4 st;
                #pragma unroll
                for (int r = 0; r < 4; ++r) {
                    const float z = v[r] + bias;
                    st[r] = f2bf(z > 0.f ? z : 0.f);
                }
                const size_t off = ((((size_t)(b * 64 + T) * 64) + (hc >> 4) * 2 + kh2) * 64
                                    + q2 * 16 + (hc & 15)) * 8 + j0;
                *(ushortx4*)(h_sw + off) = st;
            }
        }
    }
}

// ---------------------------------------------------------------------------
// Kernel 2: MFMA attention — R8's skew pipeline + TRUE 2-BLOCKS/CU via
// column-split (round-9 analysis: R8 runs 1 block/CU; R3's co-residency
// test was confounded by 2x h-traffic. This isolates it with traffic held
// constant). QT=64 kept; grid = 4b x 64qt x 2 col-halves = 512 blocks of
// 512 threads (8 waves) -> 2 blocks/CU (LDS 65KB x2 = 130 < 160; VGPR
// target <=128 via __launch_bounds__(512,4)).
//
// Scores (per 64-key half): 16 tiles / 8 waves -> wave w computes tiles
// (wr=w&3, wc=(w>>2)*2+{0,1}) — duplicated across the 2 ch-blocks (+11%
// MFMA, QK is 11% of FLOPs). PV: wave w -> rows (w>>2)*32..+32 x 64 F-cols
// (ch*256 + (w&3)*64): each A-frag feeds 4 h-frags -> A-reads HALVE
// (16->8 b128/wave/iter). h: 8 contiguous groups (8 KB)/wave/mtile, exact
// tiling; wq-twin re-reads are L1-hits. Per-CU h L2 traffic unchanged.
//
// LDS stride-128 + (row&7)<<4 XOR-swizzle (verified-0 pattern; A-frag rows
// remain 16-per-read). Skew: scores(it) || PV(it-1), setprio around PV.
// XCD map: XCD = b*2+ch -> 1 MB h-half + 512 KB g L2-resident per XCD.
// ---------------------------------------------------------------------------
#define QT 64

__global__ __launch_bounds__(512, 4) void attn_mfma_kernel(
    const unsigned short* __restrict__ f_bf, const unsigned short* __restrict__ g_bf,
    const unsigned short* __restrict__ h_sw, const float* __restrict__ gamma,
    const float* __restrict__ V, float* __restrict__ out)
{
    __shared__ __align__(16) unsigned short p_lds[2][2][QT * 64];   // 32 KB
    __shared__ __align__(16) unsigned short g_lds[2][2][64 * 64];   // 32 KB
    __shared__ float l_red[2][QT];
    __shared__ float l_inv[QT];

    const int t = threadIdx.x;
    const int w = t >> 6, lane = t & 63, quad = lane >> 4, l16 = lane & 15;
    const int wr = w & 3, wcp = w >> 2;    // scores: rows wr*16, col-pair wcp
    const int wq = w >> 2, wf = w & 3;     // PV: rows wq*32, fcols wf*64

    // bid&7 = XCD = b*2 + ch; bid>>3 = q-tile (64 per batch).
    const int bid = blockIdx.x;
    const int b   = (bid & 7) >> 1;
    const int ch  = bid & 1;
    const int qb  = bid >> 3;
    const int R0  = qb * QT;

    const unsigned short* fb    = f_bf + ((size_t)b * 4096 + R0) * C_DIM;
    const unsigned short* gb    = g_bf + (size_t)b * 4096 * C_DIM;
    const unsigned short* hbase = h_sw + (size_t)b * 64 * 32768;
    const int hgrp = ch * 32 + wf * 8;     // wave's 8 h groups (64 F-cols)

    bf16x8 f0, f1;
    {
        const unsigned short* fr = fb + (size_t)(wr * 16 + l16) * C_DIM + quad * 8;
        f0 = *(const bf16x8*)fr;
        f1 = *(const bf16x8*)(fr + 32);
    }
    float gam[4];
    #pragma unroll
    for (int cg = 0; cg < 4; ++cg)
        gam[cg] = gamma[ch * 256 + wf * 64 + cg * 16 + l16];

    floatx4 acc[2][4];   // [q-tile within wq-half][col-16-group]
    #pragma unroll
    for (int qt = 0; qt < 2; ++qt)
        #pragma unroll
        for (int cg = 0; cg < 4; ++cg)
            acc[qt][cg] = (floatx4){0.f, 0.f, 0.f, 0.f};
    float run_l[4] = {0.f, 0.f, 0.f, 0.f};

    // cooperative g stage: 512 threads x 32 B = 16 KB (both 64-key halves).
    const int grow = t >> 3, gchunk = t & 7;
    const int g_swoff = grow * 128 + ((gchunk * 16) ^ ((grow & 7) << 4));
    ushortx8 greg0 = *(const ushortx8*)(gb + (size_t)grow * C_DIM + gchunk * 8);
    ushortx8 greg1 = *(const ushortx8*)(gb + (size_t)(64 + grow) * C_DIM + gchunk * 8);

    // loop-invariant swizzled score-read offsets (2 tiles u=0,1)
    const int sgrA = (wcp * 2) * 16 + l16;
    const int sgrB = (wcp * 2 + 1) * 16 + l16;
    const int sgA0 = sgrA * 128 + ((quad * 16)      ^ ((sgrA & 7) << 4));
    const int sgA1 = sgrA * 128 + ((quad * 16 + 64) ^ ((sgrA & 7) << 4));
    const int sgB0 = sgrB * 128 + ((quad * 16)      ^ ((sgrB & 7) << 4));
    const int sgB1 = sgrB * 128 + ((quad * 16 + 64) ^ ((sgrB & 7) << 4));

    // ---- peel it=0: stage g(0), scores(0) -> p[0] ----
    *(ushortx8*)((unsigned char*)&g_lds[0][0][0] + g_swoff) = greg0;
    *(ushortx8*)((unsigned char*)&g_lds[0][1][0] + g_swoff) = greg1;
    greg0 = *(const ushortx8*)(gb + (size_t)(128 + grow) * C_DIM + gchunk * 8);
    greg1 = *(const ushortx8*)(gb + (size_t)(192 + grow) * C_DIM + gchunk * 8);
    lgkm_barrier();
    #pragma unroll
    for (int s = 0; s < 2; ++s) {
        const unsigned char* gB = (const unsigned char*)&g_lds[0][s][0];
        unsigned char*       pB = (unsigned char*)&p_lds[0][s][0];
        #pragma unroll
        for (int u = 0; u < 2; ++u) {
            const bf16x8 g0 = *(const bf16x8*)(gB + (u ? sgB0 : sgA0));
            const bf16x8 g1 = *(const bf16x8*)(gB + (u ? sgB1 : sgA1));
            floatx4 cc = (floatx4){0.f, 0.f, 0.f, 0.f};
            cc = __builtin_amdgcn_mfma_f32_16x16x32_bf16(f0, g0, cc, 0, 0, 0);
            cc = __builtin_amdgcn_mfma_f32_16x16x32_bf16(f1, g1, cc, 0, 0, 0);
            #pragma unroll
            for (int r = 0; r < 4; ++r) {
                const float p = __expf(cc[r] - 32.f);
                run_l[r] += p;
                const int prow = wr * 16 + quad * 4 + r;
                const int pcol = (wcp * 2 + u) * 16 + l16;
                *(unsigned short*)(pB + prow * 128 + ((pcol * 2) ^ ((prow & 7) << 4))) = f2bf(p);
            }
        }
    }

    bf16x8 hA[8], hB[8];

    // ---- main loop: scores(it) || PV(it-1) ----
    for (int it = 1; it < 32; ++it) {
        const int buf = it & 1, pb = buf ^ 1;

        // h for key-tile it-1, first mtile (hidden under stage+barrier+scores)
        const unsigned short* ht0 = hbase + (size_t)(2 * (it - 1)) * 32768 + (size_t)hgrp * 512;
        #pragma unroll
        for (int gi = 0; gi < 8; ++gi)
            hA[gi] = *(const bf16x8*)(ht0 + gi * 512 + (size_t)lane * 8);

        *(ushortx8*)((unsigned char*)&g_lds[buf][0][0] + g_swoff) = greg0;
        *(ushortx8*)((unsigned char*)&g_lds[buf][1][0] + g_swoff) = greg1;
        if (it < 31) {
            greg0 = *(const ushortx8*)(gb + (size_t)((it + 1) * 128 + grow) * C_DIM + gchunk * 8);
            greg1 = *(const ushortx8*)(gb + (size_t)((it + 1) * 128 + 64 + grow) * C_DIM + gchunk * 8);
        }
        lgkm_barrier();   // g[buf] + p[pb] visible

        // ---- scores(it): 2 tiles x 2 halves ----
        #pragma unroll
        for (int s = 0; s < 2; ++s) {
            const unsigned char* gB = (const unsigned char*)&g_lds[buf][s][0];
            unsigned char*       pB = (unsigned char*)&p_lds[buf][s][0];
            #pragma unroll
            for (int u = 0; u < 2; ++u) {
                const bf16x8 g0 = *(const bf16x8*)(gB + (u ? sgB0 : sgA0));
                const bf16x8 g1 = *(const bf16x8*)(gB + (u ? sgB1 : sgA1));
                floatx4 cc = (floatx4){0.f, 0.f, 0.f, 0.f};
                cc = __builtin_amdgcn_mfma_f32_16x16x32_bf16(f0, g0, cc, 0, 0, 0);
                cc = __builtin_amdgcn_mfma_f32_16x16x32_bf16(f1, g1, cc, 0, 0, 0);
                #pragma unroll
                for (int r = 0; r < 4; ++r) {
                    const float p = __expf(cc[r] - 32.f);
                    run_l[r] += p;
                    const int prow = wr * 16 + quad * 4 + r;
                    const int pcol = (wcp * 2 + u) * 16 + l16;
                    *(unsigned short*)(pB + prow * 128 + ((pcol * 2) ^ ((prow & 7) << 4))) = f2bf(p);
                }
            }
        }

        // h for key-tile it-1, second mtile
        const unsigned short* ht1 = ht0 + 32768;
        #pragma unroll
        for (int gi = 0; gi < 8; ++gi)
            hB[gi] = *(const bf16x8*)(ht1 + gi * 512 + (size_t)lane * 8);

        // ---- PV(it-1): rows wq*32..+32 x wave's 64 cols, both halves ----
        __builtin_amdgcn_s_setprio(1);
        #pragma unroll
        for (int qt = 0; qt < 2; ++qt) {
            const int prow = wq * 32 + qt * 16 + l16;
            const int sw   = (prow & 7) << 4;
            {   // half 0 (mtile A)
                const unsigned char* pB = (const unsigned char*)&p_lds[pb][0][0];
                const bf16x8 pf0 = *(const bf16x8*)(pB + prow * 128 + ((quad * 16)      ^ sw));
                const bf16x8 pf1 = *(const bf16x8*)(pB + prow * 128 + ((quad * 16 + 64) ^ sw));
                #pragma unroll
                for (int cg = 0; cg < 4; ++cg) {
                    acc[qt][cg] = __builtin_amdgcn_mfma_f32_16x16x32_bf16(pf0, hA[2 * cg],     acc[qt][cg], 0, 0, 0);
                    acc[qt][cg] = __builtin_amdgcn_mfma_f32_16x16x32_bf16(pf1, hA[2 * cg + 1], acc[qt][cg], 0, 0, 0);
                }
            }
            {   // half 1 (mtile B)
                const unsigned char* pB = (const unsigned char*)&p_lds[pb][1][0];
                const bf16x8 pf0 = *(const bf16x8*)(pB + prow * 128 + ((quad * 16)      ^ sw));
                const bf16x8 pf1 = *(const bf16x8*)(pB + prow * 128 + ((quad * 16 + 64) ^ sw));
                #pragma unroll
                for (int cg = 0; cg < 4; ++cg) {
                    acc[qt][cg] = __builtin_amdgcn_mfma_f32_16x16x32_bf16(pf0, hB[2 * cg],     acc[qt][cg], 0, 0, 0);
                    acc[qt][cg] = __builtin_amdgcn_mfma_f32_16x16x32_bf16(pf1, hB[2 * cg + 1], acc[qt][cg], 0, 0, 0);
                }
            }
        }
        __builtin_amdgcn_s_setprio(0);
    }

    // ---- tail: PV(31) from p[1] ----
    {
        const unsigned short* ht0 = hbase + (size_t)62 * 32768 + (size_t)hgrp * 512;
        const unsigned short* ht1 = ht0 + 32768;
        #pragma unroll
        for (int gi = 0; gi < 8; ++gi) {
            hA[gi] = *(const bf16x8*)(ht0 + gi * 512 + (size_t)lane * 8);
            hB[gi] = *(const bf16x8*)(ht1 + gi * 512 + (size_t)lane * 8);
        }
        lgkm_barrier();   // p[1] writes from scores(31) visible
        #pragma unroll
        for (int qt = 0; qt < 2; ++qt) {
            const int prow = wq * 32 + qt * 16 + l16;
            const int sw   = (prow & 7) << 4;
            {
                const unsigned char* pB = (const unsigned char*)&p_lds[1][0][0];
                const bf16x8 pf0 = *(const bf16x8*)(pB + prow * 128 + ((quad * 16)      ^ sw));
                const bf16x8 pf1 = *(const bf16x8*)(pB + prow * 128 + ((quad * 16 + 64) ^ sw));
                #pragma unroll
                for (int cg = 0; cg < 4; ++cg) {
                    acc[qt][cg] = __builtin_amdgcn_mfma_f32_16x16x32_bf16(pf0, hA[2 * cg],     acc[qt][cg], 0, 0, 0);
                    acc[qt][cg] = __builtin_amdgcn_mfma_f32_16x16x32_bf16(pf1, hA[2 * cg + 1], acc[qt][cg], 0, 0, 0);
                }
            }
            {
                const unsigned char* pB = (const unsigned char*)&p_lds[1][1][0];
                const bf16x8 pf0 = *(const bf16x8*)(pB + prow * 128 + ((quad * 16)      ^ sw));
                const bf16x8 pf1 = *(const bf16x8*)(pB + prow * 128 + ((quad * 16 + 64) ^ sw));
                #pragma unroll
                for (int cg = 0; cg < 4; ++cg) {
                    acc[qt][cg] = __builtin_amdgcn_mfma_f32_16x16x32_bf16(pf0, hB[2 * cg],     acc[qt][cg], 0, 0, 0);
                    acc[qt][cg] = __builtin_amdgcn_mfma_f32_16x16x32_bf16(pf1, hB[2 * cg + 1], acc[qt][cg], 0, 0, 0);
                }
            }
        }
    }

    // ---- full row-sum l: shfl over l16, then LDS-sum across the 2 wcp ----
    #pragma unroll
    for (int r = 0; r < 4; ++r) {
        float v = run_l[r];
        v += __shfl_xor(v, 1, 64);
        v += __shfl_xor(v, 2, 64);
        v += __shfl_xor(v, 4, 64);
        v += __shfl_xor(v, 8, 64);
        if (l16 == 0) l_red[wcp][wr * 16 + quad * 4 + r] = v;
    }
    __syncthreads();
    if (t < QT)
        l_inv[t] = 1.f / (l_red[0][t] + l_red[1][t]);
    __syncthreads();

    // ---- fused epilogue: out = gamma * O/l + V (fp32, final) ----
    const float* Vb = V   + ((size_t)b * 4096 + R0) * F_DIM;
    float*       ob = out + ((size_t)b * 4096 + R0) * F_DIM;
    #pragma unroll
    for (int qt = 0; qt < 2; ++qt) {
        #pragma unroll
        for (int r = 0; r < 4; ++r) {
            const int row = wq * 32 + qt * 16 + quad * 4 + r;
            const float li = l_inv[row];
            #pragma unroll
            for (int cg = 0; cg < 4; ++cg) {
                const int col = ch * 256 + wf * 64 + cg * 16 + l16;
                ob[(size_t)row * F_DIM + col] =
                    gam[cg] * acc[qt][cg][r] * li + Vb[(size_t)row * F_DIM + col];
            }
        }
    }
}

// ---------------------------------------------------------------------------
extern "C" void kernel_launch(void* const* d_in, const int* in_sizes, int n_in,
                              void* d_out, int out_size, void* d_ws, size_t ws_size,
                              hipStream_t stream) {
    const float* V     = (const float*)d_in[0];
    const float* Wf    = (const float*)d_in[1];
    const float* bf    = (const float*)d_in[2];
    const float* Wg    = (const float*)d_in[3];
    const float* bg    = (const float*)d_in[4];
    const float* Wh    = (const float*)d_in[5];
    const float* bh    = (const float*)d_in[6];
    const float* gamma = (const float*)d_in[7];
    float* out = (float*)d_out;

    // ws: f 2MB | g 2MB | h_sw 16MB | wt_hi 0.64 | wt_lo 0.64
    unsigned short* f_bf  = (unsigned short*)d_ws;
    unsigned short* g_bf  = f_bf + (size_t)M_ROWS * C_DIM;
    unsigned short* h_sw  = g_bf + (size_t)M_ROWS * C_DIM;
    unsigned short* wt_hi = h_sw + (size_t)4 * F_DIM * 4096;
    unsigned short* wt_lo = wt_hi + (size_t)640 * F_DIM;

    prep_w_kernel<<<640, 64, 0, stream>>>(Wf, Wg, Wh, wt_hi, wt_lo);
    embed_mfma_kernel<<<dim3(M_ROWS / BM, 5), 256, 0, stream>>>(
        V, wt_hi, wt_lo, bf, bg, bh, f_bf, g_bf, h_sw);
    attn_mfma_kernel<<<512, 512, 0, stream>>>(f_bf, g_bf, h_sw, gamma, V, out);
}